// Round 5
// baseline (565.278 us; speedup 1.0000x reference)
//
#include <hip/hip_runtime.h>

// Problem constants (match reference)
#define NROWS   262144
#define DIM     256
#define CLUSTER 512
#define NPAIR   (CLUSTER * (CLUSTER - 1) / 2)   // 130816
#define G       16                               // cluster groups (32 clusters each)
#define CPG     32                               // clusters per group
#define R       64                               // row chunks
#define CHUNK   (NROWS / R)                      // 4096 rows per chunk
#define PAIR_BLOCKS 2044                         // 2044 * 4 waves * 16 pairs = 130816 exactly

// ---------------- K1: local counting-sort + VGPR accumulate + atomic flush --
// Block (g, r): builds per-cluster contiguous lists of local row indices in
// LDS (count -> scan -> place), then wave w walks clusters {w, w+4, ..},
// accumulating rows in 4 VGPRs, and flushes each cluster partial with 4
// global fp32 atomicAdds per lane into the 512 KB sums buffer (L3-resident).
// No 33 MB partial round-trip, no separate reduce kernel.
__global__ __launch_bounds__(256) void k_gather(const float* __restrict__ matrix,
                                                const int* __restrict__ label,
                                                float* __restrict__ sums,     // [CLUSTER][DIM]
                                                int* __restrict__ counts) {   // [CLUSTER]
    int g = blockIdx.x & (G - 1);
    int r = blockIdx.x >> 4;           // 0..R-1
    int t = threadIdx.x;
    int w = t >> 6, lane = t & 63;
    int base = r * CHUNK;

    __shared__ unsigned short list[CHUNK];   // 8 KB, segmented by cluster
    __shared__ int cnt[CPG];
    __shared__ int off[CPG + 1];
    __shared__ int cur[CPG];

    if (t < CPG) cnt[t] = 0;
    __syncthreads();

    // pass 1: count rows per local cluster
    for (int i = t; i < CHUNK; i += 256) {
        int lab = label[base + i];
        if ((lab >> 5) == g) atomicAdd(&cnt[lab & (CPG - 1)], 1);
    }
    __syncthreads();

    // tiny exclusive scan (serial, 32 elements)
    if (t == 0) {
        int s = 0;
        #pragma unroll
        for (int c = 0; c < CPG; ++c) { off[c] = s; cur[c] = s; s += cnt[c]; }
        off[CPG] = s;
    }
    __syncthreads();

    // pass 2: place local row indices into cluster segments (labels L2-hot)
    for (int i = t; i < CHUNK; i += 256) {
        int lab = label[base + i];
        if ((lab >> 5) == g) {
            int p = atomicAdd(&cur[lab & (CPG - 1)], 1);
            list[p] = (unsigned short)i;
        }
    }
    __syncthreads();

    // accumulate: wave w owns clusters cl = 4q + w, acc in VGPRs, atomic flush
    #pragma unroll
    for (int q = 0; q < 8; ++q) {
        int cl = q * 4 + w;
        int s0 = off[cl], s1 = off[cl + 1];
        if (s0 == s1) continue;
        float ax = 0.f, ay = 0.f, az = 0.f, aw = 0.f;
        #pragma unroll 4
        for (int k = s0; k < s1; ++k) {
            int li = list[k];   // wave-uniform LDS broadcast
            const float4* row = (const float4*)(matrix + (size_t)(base + li) * DIM);
            float4 v = row[lane];
            ax += v.x; ay += v.y; az += v.z; aw += v.w;
        }
        float* dst = sums + ((size_t)(g * CPG + cl)) * DIM + lane * 4;
        atomicAdd(dst + 0, ax);
        atomicAdd(dst + 1, ay);
        atomicAdd(dst + 2, az);
        atomicAdd(dst + 3, aw);
    }
    if (t < CPG && cnt[t]) atomicAdd(&counts[g * CPG + t], cnt[t]);
}

// ---------------- K2: normalize sums -> centers (one float4 per thread) -----
__global__ __launch_bounds__(256) void k_norm(const float* __restrict__ sums,
                                              const int* __restrict__ counts,
                                              float* __restrict__ centers) {
    int idx = blockIdx.x * 256 + threadIdx.x;    // 32768 float4s total
    int c = idx >> 6;                            // 64 float4 per cluster
    float inv = 1.0f / (float)max(counts[c], 1);
    float4 s = ((const float4*)sums)[idx];
    s.x *= inv; s.y *= inv; s.z *= inv; s.w *= inv;
    ((float4*)centers)[idx] = s;
}

// ---------------- K3: pairwise distances, 16 pairs per wave -----------------
__device__ __forceinline__ long long tri_off(long long i) {
    return i * (2 * CLUSTER - i - 1) / 2;
}

__global__ __launch_bounds__(256) void k_pairs(const float* __restrict__ centers,
                                               float* __restrict__ partials) {
    int wave = threadIdx.x >> 6;
    int lane = threadIdx.x & 63;
    long long base = ((long long)blockIdx.x * 4 + wave) * 16;  // first pair, < NPAIR

    // invert triangular index once per wave
    double sq = sqrt((double)((2LL * CLUSTER - 1) * (2LL * CLUSTER - 1) - 8 * base));
    int i = (int)(((2 * CLUSTER - 1) - sq) * 0.5);
    if (i < 0) i = 0;
    while (tri_off(i + 1) <= base) ++i;
    while (tri_off(i) > base) --i;
    int j = (int)(base - tri_off(i)) + i + 1;

    float wsum = 0.f;
    #pragma unroll 4
    for (int q = 0; q < 16; ++q) {
        const float4* ci = (const float4*)(centers + (size_t)i * DIM);
        const float4* cj = (const float4*)(centers + (size_t)j * DIM);
        float4 a = ci[lane], b = cj[lane];
        float dx = a.x - b.x, dy = a.y - b.y, dz = a.z - b.z, dw = a.w - b.w;
        float local = dx * dx + dy * dy + dz * dz + dw * dw;
        #pragma unroll
        for (int o = 32; o; o >>= 1) local += __shfl_xor(local, o, 64);
        wsum += sqrtf(fmaxf(local, 1e-12f));
        if (++j == CLUSTER) { ++i; j = i + 1; }
    }

    __shared__ float bsum[4];
    if (lane == 0) bsum[wave] = wsum;
    __syncthreads();
    if (threadIdx.x == 0)
        partials[blockIdx.x] = bsum[0] + bsum[1] + bsum[2] + bsum[3];
}

// ---------------- K4: final reduce of block partials -> -mean ---------------
__global__ __launch_bounds__(256) void k_final(const float* __restrict__ partials, int nb,
                                               float* __restrict__ out) {
    __shared__ float s[256];
    float acc = 0.f;
    for (int i = threadIdx.x; i < nb; i += 256) acc += partials[i];
    s[threadIdx.x] = acc;
    __syncthreads();
    for (int d = 128; d; d >>= 1) {
        if (threadIdx.x < d) s[threadIdx.x] += s[threadIdx.x + d];
        __syncthreads();
    }
    if (threadIdx.x == 0) out[0] = -s[0] / (float)NPAIR;
}

extern "C" void kernel_launch(void* const* d_in, const int* in_sizes, int n_in,
                              void* d_out, int out_size, void* d_ws, size_t ws_size,
                              hipStream_t stream) {
    const float* matrix = (const float*)d_in[0];
    const int* label = (const int*)d_in[1];
    float* out = (float*)d_out;

    // workspace layout (floats unless noted); sums+counts zeroed each call
    float* sums    = (float*)d_ws;                        // 512*256 = 131072 floats
    int*   counts  = (int*)(sums + (size_t)CLUSTER * DIM);// 512 ints (contiguous w/ sums)
    float* centers = (float*)(counts + CLUSTER);          // 131072 floats
    float* ppart   = centers + (size_t)CLUSTER * DIM;     // 2044 floats

    hipMemsetAsync(sums, 0, (size_t)CLUSTER * DIM * sizeof(float) + CLUSTER * sizeof(int),
                   stream);
    k_gather<<<G * R, 256, 0, stream>>>(matrix, label, sums, counts);
    k_norm<<<CLUSTER * DIM / 4 / 256, 256, 0, stream>>>(sums, counts, centers);
    k_pairs<<<PAIR_BLOCKS, 256, 0, stream>>>(centers, ppart);
    k_final<<<1, 256, 0, stream>>>(ppart, PAIR_BLOCKS, out);
}

// Round 6
// 420.838 us; speedup vs baseline: 1.3432x; 1.3432x over previous
//
#include <hip/hip_runtime.h>

// Problem constants (match reference)
#define NROWS   262144
#define DIM     256
#define CLUSTER 512
#define NPAIR   (CLUSTER * (CLUSTER - 1) / 2)   // 130816
#define G       16                               // cluster groups (32 clusters each)
#define CPG     32                               // clusters per group
#define R       64                               // row chunks
#define CHUNK   (NROWS / R)                      // 4096 rows per chunk
#define PF      8                                // prefetch depth (8 float4 in flight/wave)
#define PAIR_BLOCKS 2044                         // 2044 * 4 waves * 16 pairs = 130816 exactly

// ---------------- K1: local counting-sort + pipelined streaming accumulate --
// Block (g, r): counting-sorts its 4096 labels into per-cluster LDS segments,
// then wave w streams the CONTIGUOUS list range of clusters [8w, 8w+8) with an
// 8-deep rotating float4 prefetch buffer (8 independent global loads always in
// flight), flushing the VGPR accumulator to the partials buffer at segment
// boundaries. Matrix rows are read exactly once device-wide; no atomics on the
// hot path. (R5 lesson: global f32 atomic flush = 60 Gop/s, 131 MB writeback.)
__global__ __launch_bounds__(256) void k_gather(const float* __restrict__ matrix,
                                                const int* __restrict__ label,
                                                float* __restrict__ partial,    // [CLUSTER][R][DIM]
                                                int* __restrict__ countpart) {  // [R][CLUSTER]
    int g = blockIdx.x & (G - 1);
    int r = blockIdx.x >> 4;           // 0..R-1
    int t = threadIdx.x;
    int w = t >> 6, lane = t & 63;
    int base = r * CHUNK;

    __shared__ unsigned short list[CHUNK];   // 8 KB, segmented by cluster
    __shared__ int cnt[CPG];
    __shared__ int off[CPG + 1];
    __shared__ int cur[CPG];

    if (t < CPG) cnt[t] = 0;
    __syncthreads();

    // pass 1: count rows per local cluster (int4-vectorized label reads)
    const int4* lab4 = (const int4*)(label + base);
    for (int i = t; i < CHUNK / 4; i += 256) {
        int4 L = lab4[i];
        if ((L.x >> 5) == g) atomicAdd(&cnt[L.x & (CPG - 1)], 1);
        if ((L.y >> 5) == g) atomicAdd(&cnt[L.y & (CPG - 1)], 1);
        if ((L.z >> 5) == g) atomicAdd(&cnt[L.z & (CPG - 1)], 1);
        if ((L.w >> 5) == g) atomicAdd(&cnt[L.w & (CPG - 1)], 1);
    }
    __syncthreads();

    // tiny exclusive scan (serial, 32 elements)
    if (t == 0) {
        int s = 0;
        #pragma unroll
        for (int c = 0; c < CPG; ++c) { off[c] = s; cur[c] = s; s += cnt[c]; }
        off[CPG] = s;
    }
    __syncthreads();

    // pass 2: place local row indices into cluster segments (labels L2-hot)
    for (int i = t; i < CHUNK / 4; i += 256) {
        int4 L = lab4[i];
        int i4 = i * 4;
        if ((L.x >> 5) == g) list[atomicAdd(&cur[L.x & (CPG - 1)], 1)] = (unsigned short)(i4 + 0);
        if ((L.y >> 5) == g) list[atomicAdd(&cur[L.y & (CPG - 1)], 1)] = (unsigned short)(i4 + 1);
        if ((L.z >> 5) == g) list[atomicAdd(&cur[L.z & (CPG - 1)], 1)] = (unsigned short)(i4 + 2);
        if ((L.w >> 5) == g) list[atomicAdd(&cur[L.w & (CPG - 1)], 1)] = (unsigned short)(i4 + 3);
    }
    __syncthreads();

    // wave w streams clusters [8w, 8w+8) as one contiguous list range
    int c0 = w * 8;
    int lo = off[c0], hi = off[c0 + 8];
    int seg = c0;
    int nextb = off[seg + 1];
    float ax = 0.f, ay = 0.f, az = 0.f, aq = 0.f;

    float4 pv[PF];
    #pragma unroll
    for (int d = 0; d < PF; ++d) {
        int k = lo + d;
        int li = (k < hi) ? (int)list[k] : 0;          // dummy (row 0 of chunk) if OOB
        pv[d] = ((const float4*)(matrix + (size_t)(base + li) * DIM))[lane];
    }

    for (int k0 = lo; k0 < hi; k0 += PF) {
        #pragma unroll
        for (int d = 0; d < PF; ++d) {
            int k = k0 + d;
            if (k >= hi) break;                         // wave-uniform
            float4 v = pv[d];
            int kn = k + PF;
            if (kn < hi) {                              // refill slot immediately
                int li = list[kn];
                pv[d] = ((const float4*)(matrix + (size_t)(base + li) * DIM))[lane];
            }
            while (k >= nextb) {                        // flush finished segment(s)
                ((float4*)(partial + ((size_t)(g * CPG + seg) * R + r) * DIM))[lane] =
                    make_float4(ax, ay, az, aq);
                ax = ay = az = aq = 0.f;
                ++seg; nextb = off[seg + 1];
            }
            ax += v.x; ay += v.y; az += v.z; aq += v.w;
        }
    }
    while (seg < c0 + 8) {                              // flush tail (+empty segments)
        ((float4*)(partial + ((size_t)(g * CPG + seg) * R + r) * DIM))[lane] =
            make_float4(ax, ay, az, aq);
        ax = ay = az = aq = 0.f;
        ++seg;
    }
    if (t < CPG) countpart[r * CLUSTER + g * CPG + t] = cnt[t];
}

// ---------------- K2: reduce chunk partials -> centers ----------------------
__global__ __launch_bounds__(256) void k_center(const float* __restrict__ partial,
                                                const int* __restrict__ countpart,
                                                float* __restrict__ centers) {
    int c = blockIdx.x, t = threadIdx.x;
    __shared__ float sinv;
    // parallel count reduce: 64 lanes of wave 0 + shuffle
    if (t < 64) {
        int cv = countpart[t * CLUSTER + c];
        #pragma unroll
        for (int o = 32; o; o >>= 1) cv += __shfl_down(cv, o, 64);
        if (t == 0) sinv = 1.0f / (float)max(cv, 1);
    }
    float acc = 0.f;
    const float* p = partial + (size_t)c * R * DIM + t;   // contiguous 64 KB per block
    #pragma unroll 8
    for (int r = 0; r < R; ++r) acc += p[r * DIM];
    __syncthreads();
    centers[c * DIM + t] = acc * sinv;
}

// ---------------- K3: pairwise distances, 16 pairs per wave, fused final ----
__device__ __forceinline__ long long tri_off(long long i) {
    return i * (2 * CLUSTER - i - 1) / 2;
}

__global__ __launch_bounds__(256) void k_pairs(const float* __restrict__ centers,
                                               float* __restrict__ out) {
    int wave = threadIdx.x >> 6;
    int lane = threadIdx.x & 63;
    long long base = ((long long)blockIdx.x * 4 + wave) * 16;  // first pair, < NPAIR

    // invert triangular index once per wave
    double sq = sqrt((double)((2LL * CLUSTER - 1) * (2LL * CLUSTER - 1) - 8 * base));
    int i = (int)(((2 * CLUSTER - 1) - sq) * 0.5);
    if (i < 0) i = 0;
    while (tri_off(i + 1) <= base) ++i;
    while (tri_off(i) > base) --i;
    int j = (int)(base - tri_off(i)) + i + 1;

    float wsum = 0.f;
    #pragma unroll 4
    for (int q = 0; q < 16; ++q) {
        const float4* ci = (const float4*)(centers + (size_t)i * DIM);
        const float4* cj = (const float4*)(centers + (size_t)j * DIM);
        float4 a = ci[lane], b = cj[lane];
        float dx = a.x - b.x, dy = a.y - b.y, dz = a.z - b.z, dw = a.w - b.w;
        float local = dx * dx + dy * dy + dz * dz + dw * dw;
        #pragma unroll
        for (int o = 32; o; o >>= 1) local += __shfl_xor(local, o, 64);
        wsum += sqrtf(fmaxf(local, 1e-12f));
        if (++j == CLUSTER) { ++i; j = i + 1; }
    }

    __shared__ float bsum[4];
    if (lane == 0) bsum[wave] = wsum;
    __syncthreads();
    if (threadIdx.x == 0)
        atomicAdd(out, (bsum[0] + bsum[1] + bsum[2] + bsum[3]) * (-1.0f / (float)NPAIR));
}

extern "C" void kernel_launch(void* const* d_in, const int* in_sizes, int n_in,
                              void* d_out, int out_size, void* d_ws, size_t ws_size,
                              hipStream_t stream) {
    const float* matrix = (const float*)d_in[0];
    const int* label = (const int*)d_in[1];
    float* out = (float*)d_out;

    // workspace layout (all fully overwritten each call; ~33 MB)
    float* partial   = (float*)d_ws;                                  // 512*64*256 floats = 32 MB
    float* centers   = partial + (size_t)CLUSTER * R * DIM;           // 512*256 floats
    int*   countpart = (int*)(centers + (size_t)CLUSTER * DIM);       // 64*512 ints

    hipMemsetAsync(out, 0, sizeof(float), stream);   // k_pairs accumulates atomically
    k_gather<<<G * R, 256, 0, stream>>>(matrix, label, partial, countpart);
    k_center<<<CLUSTER, 256, 0, stream>>>(partial, countpart, centers);
    k_pairs<<<PAIR_BLOCKS, 256, 0, stream>>>(centers, out);
}